// Round 1
// baseline (1524.946 us; speedup 1.0000x reference)
//
#include <hip/hip_runtime.h>
#include <math.h>

#define B_  4
#define S_  2048
#define D_  512
#define H_  8
#define DK  64
#define BS_ (B_ * S_)      // 8192
#define LNEPS 1e-5f
#define NEG_INF (-__builtin_inff())

// ---------------------------------------------------------------------------
// Kernel 1: per-row LayerNorm stats (mean, rsqrt(var+eps)) for q, k, v.
// One wave (64 lanes) per row of 512 floats. stats layout: [3][8192][2].
// ---------------------------------------------------------------------------
__global__ __launch_bounds__(256)
void ln_stats_kernel(const float* __restrict__ q, const float* __restrict__ k,
                     const float* __restrict__ v, float* __restrict__ stats) {
    int gwave = (blockIdx.x * 256 + threadIdx.x) >> 6;   // 0..24575
    int lane  = threadIdx.x & 63;
    int which = gwave >> 13;          // /8192 -> 0,1,2
    int row   = gwave & 8191;
    const float* src = (which == 0) ? q : ((which == 1) ? k : v);
    const float4* p = reinterpret_cast<const float4*>(src + (size_t)row * D_);
    float4 a = p[lane];
    float4 b = p[lane + 64];
    float sum = a.x + a.y + a.z + a.w + b.x + b.y + b.z + b.w;
    float sq  = a.x*a.x + a.y*a.y + a.z*a.z + a.w*a.w
              + b.x*b.x + b.y*b.y + b.z*b.z + b.w*b.w;
#pragma unroll
    for (int off = 32; off > 0; off >>= 1) {
        sum += __shfl_down(sum, off);
        sq  += __shfl_down(sq,  off);
    }
    if (lane == 0) {
        float mu  = sum * (1.0f / D_);
        float var = sq * (1.0f / D_) - mu * mu;
        stats[(size_t)gwave * 2 + 0] = mu;
        stats[(size_t)gwave * 2 + 1] = rsqrtf(var + LNEPS);
    }
}

// ---------------------------------------------------------------------------
// Kernel 2: fused LayerNorm + projection GEMM.
// C[8192,512] = LN(src) @ W + bias, written head-split to dst[B,H,S,DK].
// 128x128 block tile, 16-deep K tiles, 8x8 per-thread microtile.
// ---------------------------------------------------------------------------
__global__ __launch_bounds__(256)
void qkv_proj_kernel(const float* __restrict__ src, const float* __restrict__ W,
                     const float* __restrict__ bias,
                     const float* __restrict__ gamma, const float* __restrict__ beta,
                     const float* __restrict__ stats,   // [8192][2] for this src
                     float* __restrict__ dst) {
    __shared__ __align__(16) float As[16][132];   // [k][m], padded (store conflicts)
    __shared__ __align__(16) float Bs[16][128];   // [k][n]
    __shared__ float gs[D_];
    __shared__ float bs[D_];
    int tid = threadIdx.x;
    gs[tid] = gamma[tid]; gs[tid + 256] = gamma[tid + 256];
    bs[tid] = beta[tid];  bs[tid + 256] = beta[tid + 256];

    int rb = blockIdx.x * 128;
    int cb = blockIdx.y * 128;
    int tr = tid >> 4, tc = tid & 15;
    int ar0 = tid >> 2;              // 0..63 (A-load row, fixed per thread)
    int ac4 = (tid & 3) * 4;         // 0,4,8,12
    int br0 = tid >> 5;              // 0..7
    int bc4 = (tid & 31) * 4;        // 0..124

    float mu0 = stats[(rb + ar0) * 2 + 0];
    float rs0 = stats[(rb + ar0) * 2 + 1];
    float mu1 = stats[(rb + ar0 + 64) * 2 + 0];
    float rs1 = stats[(rb + ar0 + 64) * 2 + 1];

    float acc[8][8];
#pragma unroll
    for (int i = 0; i < 8; ++i)
#pragma unroll
        for (int j = 0; j < 8; ++j) acc[i][j] = 0.0f;

    __syncthreads();   // gs/bs ready
    for (int kt = 0; kt < 32; ++kt) {
        int k0 = kt * 16;
        float4 v0 = *(const float4*)&src[(size_t)(rb + ar0) * D_ + k0 + ac4];
        float4 v1 = *(const float4*)&src[(size_t)(rb + ar0 + 64) * D_ + k0 + ac4];
#pragma unroll
        for (int j = 0; j < 4; ++j) {
            int kk = ac4 + j;
            float g = gs[k0 + kk], bb = bs[k0 + kk];
            As[kk][ar0]      = (((const float*)&v0)[j] - mu0) * rs0 * g + bb;
            As[kk][ar0 + 64] = (((const float*)&v1)[j] - mu1) * rs1 * g + bb;
        }
        *(float4*)&Bs[br0][bc4]     = *(const float4*)&W[(size_t)(k0 + br0) * D_ + cb + bc4];
        *(float4*)&Bs[br0 + 8][bc4] = *(const float4*)&W[(size_t)(k0 + br0 + 8) * D_ + cb + bc4];
        __syncthreads();
#pragma unroll
        for (int kk = 0; kk < 16; ++kk) {
            float4 a0 = *(const float4*)&As[kk][tr * 8];
            float4 a1 = *(const float4*)&As[kk][tr * 8 + 4];
            float4 b0 = *(const float4*)&Bs[kk][tc * 8];
            float4 b1 = *(const float4*)&Bs[kk][tc * 8 + 4];
            float av[8] = {a0.x, a0.y, a0.z, a0.w, a1.x, a1.y, a1.z, a1.w};
            float bv[8] = {b0.x, b0.y, b0.z, b0.w, b1.x, b1.y, b1.z, b1.w};
#pragma unroll
            for (int i = 0; i < 8; ++i)
#pragma unroll
                for (int j = 0; j < 8; ++j)
                    acc[i][j] = fmaf(av[i], bv[j], acc[i][j]);
        }
        __syncthreads();
    }
#pragma unroll
    for (int i = 0; i < 8; ++i) {
        int gr = rb + tr * 8 + i;
        int b = gr >> 11, s = gr & 2047;
#pragma unroll
        for (int j = 0; j < 8; j += 4) {
            int col = cb + tc * 8 + j;
            int h = col >> 6, dkk = col & 63;
            float4 o;
            o.x = acc[i][j + 0] + bias[col + 0];
            o.y = acc[i][j + 1] + bias[col + 1];
            o.z = acc[i][j + 2] + bias[col + 2];
            o.w = acc[i][j + 3] + bias[col + 3];
            *(float4*)&dst[((size_t)(b * H_ + h) * S_ + s) * DK + dkk] = o;
        }
    }
}

// ---------------------------------------------------------------------------
// Kernel 3: scores = qh @ kh^T * 0.125 + pos_k, mask==0 -> -inf.
// Written directly to the attn region of d_out (raw, pre-softmax).
// Per bh: M=N=2048, K=64. 128x128 tiles.
// ---------------------------------------------------------------------------
__global__ __launch_bounds__(256)
void scores_kernel(const float* __restrict__ qh, const float* __restrict__ kh,
                   const float* __restrict__ pos, const int* __restrict__ mask,
                   float* __restrict__ attn) {
    int bh = blockIdx.z;
    const float* A  = qh + (size_t)bh * S_ * DK;
    const float* Bk = kh + (size_t)bh * S_ * DK;
    __shared__ __align__(16) float As[16][132];
    __shared__ __align__(16) float Bs[16][132];
    int tid = threadIdx.x;
    int rb = blockIdx.x * 128, cb = blockIdx.y * 128;
    int tr = tid >> 4, tc = tid & 15;
    int ar0 = tid >> 2;
    int ac4 = (tid & 3) * 4;

    float acc[8][8];
#pragma unroll
    for (int i = 0; i < 8; ++i)
#pragma unroll
        for (int j = 0; j < 8; ++j) acc[i][j] = 0.0f;

    for (int kt = 0; kt < 4; ++kt) {
        int k0 = kt * 16;
        float4 v0 = *(const float4*)&A [(size_t)(rb + ar0) * DK + k0 + ac4];
        float4 v1 = *(const float4*)&A [(size_t)(rb + ar0 + 64) * DK + k0 + ac4];
        float4 w0 = *(const float4*)&Bk[(size_t)(cb + ar0) * DK + k0 + ac4];
        float4 w1 = *(const float4*)&Bk[(size_t)(cb + ar0 + 64) * DK + k0 + ac4];
#pragma unroll
        for (int j = 0; j < 4; ++j) {
            int kk = ac4 + j;
            As[kk][ar0]      = ((const float*)&v0)[j];
            As[kk][ar0 + 64] = ((const float*)&v1)[j];
            Bs[kk][ar0]      = ((const float*)&w0)[j];
            Bs[kk][ar0 + 64] = ((const float*)&w1)[j];
        }
        __syncthreads();
#pragma unroll
        for (int kk = 0; kk < 16; ++kk) {
            float4 a0 = *(const float4*)&As[kk][tr * 8];
            float4 a1 = *(const float4*)&As[kk][tr * 8 + 4];
            float4 b0 = *(const float4*)&Bs[kk][tc * 8];
            float4 b1 = *(const float4*)&Bs[kk][tc * 8 + 4];
            float av[8] = {a0.x, a0.y, a0.z, a0.w, a1.x, a1.y, a1.z, a1.w};
            float bv[8] = {b0.x, b0.y, b0.z, b0.w, b1.x, b1.y, b1.z, b1.w};
#pragma unroll
            for (int i = 0; i < 8; ++i)
#pragma unroll
                for (int j = 0; j < 8; ++j)
                    acc[i][j] = fmaf(av[i], bv[j], acc[i][j]);
        }
        __syncthreads();
    }
#pragma unroll
    for (int i = 0; i < 8; ++i) {
        int m = rb + tr * 8 + i;
        size_t rowoff = (size_t)m * S_;
#pragma unroll
        for (int j = 0; j < 8; j += 4) {
            int n = cb + tc * 8 + j;
            float4 pv = *(const float4*)&pos[rowoff + n];
            int4   mk = *(const int4*)&mask[rowoff + n];
            float4 o;
            o.x = (mk.x == 0) ? NEG_INF : fmaf(acc[i][j + 0], 0.125f, pv.x);
            o.y = (mk.y == 0) ? NEG_INF : fmaf(acc[i][j + 1], 0.125f, pv.y);
            o.z = (mk.z == 0) ? NEG_INF : fmaf(acc[i][j + 2], 0.125f, pv.z);
            o.w = (mk.w == 0) ? NEG_INF : fmaf(acc[i][j + 3], 0.125f, pv.w);
            *(float4*)&attn[((size_t)bh * S_ + m) * S_ + n] = o;
        }
    }
}

// ---------------------------------------------------------------------------
// Kernel 4: in-place row softmax on attn. One block (256 thr) per row of 2048.
// ---------------------------------------------------------------------------
__global__ __launch_bounds__(256)
void softmax_kernel(float* __restrict__ attn) {
    size_t row = blockIdx.x;                 // 0..65535
    float* p = attn + row * (size_t)S_;
    int tid = threadIdx.x;
    int wave = tid >> 6, lane = tid & 63;
    __shared__ float smax[4];
    __shared__ float ssum[4];

    float4 v0 = ((const float4*)p)[tid];
    float4 v1 = ((const float4*)p)[tid + 256];
    float m = fmaxf(fmaxf(fmaxf(v0.x, v0.y), fmaxf(v0.z, v0.w)),
                    fmaxf(fmaxf(v1.x, v1.y), fmaxf(v1.z, v1.w)));
#pragma unroll
    for (int off = 32; off > 0; off >>= 1) m = fmaxf(m, __shfl_down(m, off));
    if (lane == 0) smax[wave] = m;
    __syncthreads();
    float mall = fmaxf(fmaxf(smax[0], smax[1]), fmaxf(smax[2], smax[3]));

    float e0x = expf(v0.x - mall), e0y = expf(v0.y - mall);
    float e0z = expf(v0.z - mall), e0w = expf(v0.w - mall);
    float e1x = expf(v1.x - mall), e1y = expf(v1.y - mall);
    float e1z = expf(v1.z - mall), e1w = expf(v1.w - mall);
    float s = e0x + e0y + e0z + e0w + e1x + e1y + e1z + e1w;
#pragma unroll
    for (int off = 32; off > 0; off >>= 1) s += __shfl_down(s, off);
    if (lane == 0) ssum[wave] = s;
    __syncthreads();
    float total = ssum[0] + ssum[1] + ssum[2] + ssum[3];
    float inv = 1.0f / total;

    float4 o0 = {e0x * inv, e0y * inv, e0z * inv, e0w * inv};
    float4 o1 = {e1x * inv, e1y * inv, e1z * inv, e1w * inv};
    ((float4*)p)[tid]       = o0;
    ((float4*)p)[tid + 256] = o1;
}

// ---------------------------------------------------------------------------
// Kernel 5: x = attn @ vh. Per bh: M=2048, N=64, K=2048. 128x64 tile, Kt=32.
// Output written interleaved back to [B, S, D] rows (for the final GEMM).
// ---------------------------------------------------------------------------
__global__ __launch_bounds__(256)
void pv_kernel(const float* __restrict__ attn, const float* __restrict__ vh,
               float* __restrict__ x) {
    int bh = blockIdx.z;
    int b = bh >> 3, h = bh & 7;
    const float* A  = attn + (size_t)bh * S_ * S_;
    const float* Bv = vh + (size_t)bh * S_ * DK;
    __shared__ __align__(16) float As[32][136];   // [k][m], padded
    __shared__ __align__(16) float Bs[32][64];    // [k][n]
    int tid = threadIdx.x;
    int rb = blockIdx.x * 128;
    int tr = tid >> 4, tc = tid & 15;
    int ar  = tid >> 3;          // 0..31
    int ac4 = (tid & 7) * 4;     // 0..28
    int br  = tid >> 4;          // 0..15
    int bc4 = (tid & 15) * 4;    // 0..60

    float acc[8][4];
#pragma unroll
    for (int i = 0; i < 8; ++i)
#pragma unroll
        for (int j = 0; j < 4; ++j) acc[i][j] = 0.0f;

    for (int kt = 0; kt < 64; ++kt) {
        int k0 = kt * 32;
#pragma unroll
        for (int l = 0; l < 4; ++l) {
            int row = ar + l * 32;
            float4 v4 = *(const float4*)&A[(size_t)(rb + row) * S_ + k0 + ac4];
            As[ac4 + 0][row] = v4.x;
            As[ac4 + 1][row] = v4.y;
            As[ac4 + 2][row] = v4.z;
            As[ac4 + 3][row] = v4.w;
        }
        *(float4*)&Bs[br][bc4]      = *(const float4*)&Bv[(size_t)(k0 + br) * DK + bc4];
        *(float4*)&Bs[br + 16][bc4] = *(const float4*)&Bv[(size_t)(k0 + br + 16) * DK + bc4];
        __syncthreads();
#pragma unroll
        for (int kk = 0; kk < 32; ++kk) {
            float4 a0 = *(const float4*)&As[kk][tr * 8];
            float4 a1 = *(const float4*)&As[kk][tr * 8 + 4];
            float4 b0 = *(const float4*)&Bs[kk][tc * 4];
            float av[8] = {a0.x, a0.y, a0.z, a0.w, a1.x, a1.y, a1.z, a1.w};
            float bv4[4] = {b0.x, b0.y, b0.z, b0.w};
#pragma unroll
            for (int i = 0; i < 8; ++i)
#pragma unroll
                for (int j = 0; j < 4; ++j)
                    acc[i][j] = fmaf(av[i], bv4[j], acc[i][j]);
        }
        __syncthreads();
    }
#pragma unroll
    for (int i = 0; i < 8; ++i) {
        int m = rb + tr * 8 + i;
        float4 o = {acc[i][0], acc[i][1], acc[i][2], acc[i][3]};
        *(float4*)&x[((size_t)b * S_ + m) * D_ + h * DK + tc * 4] = o;
    }
}

// ---------------------------------------------------------------------------
// Kernel 6: out = (x @ wo + bo) * layer_scale. Same tiling as proj, no LN.
// ---------------------------------------------------------------------------
__global__ __launch_bounds__(256)
void out_proj_kernel(const float* __restrict__ src, const float* __restrict__ W,
                     const float* __restrict__ bias, const float* __restrict__ ls,
                     float* __restrict__ dst) {
    __shared__ __align__(16) float As[16][132];
    __shared__ __align__(16) float Bs[16][128];
    int tid = threadIdx.x;
    int rb = blockIdx.x * 128;
    int cb = blockIdx.y * 128;
    int tr = tid >> 4, tc = tid & 15;
    int ar0 = tid >> 2;
    int ac4 = (tid & 3) * 4;
    int br0 = tid >> 5;
    int bc4 = (tid & 31) * 4;

    float acc[8][8];
#pragma unroll
    for (int i = 0; i < 8; ++i)
#pragma unroll
        for (int j = 0; j < 8; ++j) acc[i][j] = 0.0f;

    for (int kt = 0; kt < 32; ++kt) {
        int k0 = kt * 16;
        float4 v0 = *(const float4*)&src[(size_t)(rb + ar0) * D_ + k0 + ac4];
        float4 v1 = *(const float4*)&src[(size_t)(rb + ar0 + 64) * D_ + k0 + ac4];
#pragma unroll
        for (int j = 0; j < 4; ++j) {
            int kk = ac4 + j;
            As[kk][ar0]      = ((const float*)&v0)[j];
            As[kk][ar0 + 64] = ((const float*)&v1)[j];
        }
        *(float4*)&Bs[br0][bc4]     = *(const float4*)&W[(size_t)(k0 + br0) * D_ + cb + bc4];
        *(float4*)&Bs[br0 + 8][bc4] = *(const float4*)&W[(size_t)(k0 + br0 + 8) * D_ + cb + bc4];
        __syncthreads();
#pragma unroll
        for (int kk = 0; kk < 16; ++kk) {
            float4 a0 = *(const float4*)&As[kk][tr * 8];
            float4 a1 = *(const float4*)&As[kk][tr * 8 + 4];
            float4 b0 = *(const float4*)&Bs[kk][tc * 8];
            float4 b1 = *(const float4*)&Bs[kk][tc * 8 + 4];
            float av[8] = {a0.x, a0.y, a0.z, a0.w, a1.x, a1.y, a1.z, a1.w};
            float bv[8] = {b0.x, b0.y, b0.z, b0.w, b1.x, b1.y, b1.z, b1.w};
#pragma unroll
            for (int i = 0; i < 8; ++i)
#pragma unroll
                for (int j = 0; j < 8; ++j)
                    acc[i][j] = fmaf(av[i], bv[j], acc[i][j]);
        }
        __syncthreads();
    }
#pragma unroll
    for (int i = 0; i < 8; ++i) {
        int gr = rb + tr * 8 + i;
#pragma unroll
        for (int j = 0; j < 8; j += 4) {
            int col = cb + tc * 8 + j;
            float4 o;
            o.x = (acc[i][j + 0] + bias[col + 0]) * ls[col + 0];
            o.y = (acc[i][j + 1] + bias[col + 1]) * ls[col + 1];
            o.z = (acc[i][j + 2] + bias[col + 2]) * ls[col + 2];
            o.w = (acc[i][j + 3] + bias[col + 3]) * ls[col + 3];
            *(float4*)&dst[(size_t)gr * D_ + col] = o;
        }
    }
}

// ---------------------------------------------------------------------------
extern "C" void kernel_launch(void* const* d_in, const int* in_sizes, int n_in,
                              void* d_out, int out_size, void* d_ws, size_t ws_size,
                              hipStream_t stream) {
    const float* q    = (const float*)d_in[0];
    const float* k    = (const float*)d_in[1];
    const float* v    = (const float*)d_in[2];
    const int*   mask = (const int*)  d_in[3];
    const float* pos  = (const float*)d_in[4];
    const float* ln_g = (const float*)d_in[5];
    const float* ln_b = (const float*)d_in[6];
    const float* wq   = (const float*)d_in[7];
    const float* bq   = (const float*)d_in[8];
    const float* wk   = (const float*)d_in[9];
    const float* bk   = (const float*)d_in[10];
    const float* wv   = (const float*)d_in[11];
    const float* bv   = (const float*)d_in[12];
    const float* wo   = (const float*)d_in[13];
    const float* bo   = (const float*)d_in[14];
    const float* ls   = (const float*)d_in[15];

    float* out  = (float*)d_out;                       // [B,S,D] = 4194304 floats
    float* attn = out + (size_t)B_ * S_ * D_;          // [B,H,S,S]

    float* ws    = (float*)d_ws;
    float* qh    = ws;                                 // [B,H,S,DK]
    float* kh    = qh + (size_t)B_ * H_ * S_ * DK;
    float* vh    = kh + (size_t)B_ * H_ * S_ * DK;
    float* stats = vh + (size_t)B_ * H_ * S_ * DK;     // [3][8192][2]
    float* x     = qh;   // qh is dead after scores_kernel; reuse for attn@vh

    ln_stats_kernel<<<6144, 256, 0, stream>>>(q, k, v, stats);

    dim3 gproj(64, 4);
    qkv_proj_kernel<<<gproj, 256, 0, stream>>>(q, wq, bq, ln_g, ln_b, stats,             qh);
    qkv_proj_kernel<<<gproj, 256, 0, stream>>>(k, wk, bk, ln_g, ln_b, stats + 2 * BS_,   kh);
    qkv_proj_kernel<<<gproj, 256, 0, stream>>>(v, wv, bv, ln_g, ln_b, stats + 4 * BS_,   vh);

    scores_kernel<<<dim3(16, 16, 32), 256, 0, stream>>>(qh, kh, pos, mask, attn);
    softmax_kernel<<<65536, 256, 0, stream>>>(attn);
    pv_kernel<<<dim3(16, 1, 32), 256, 0, stream>>>(attn, vh, x);
    out_proj_kernel<<<gproj, 256, 0, stream>>>(x, wo, bo, ls, out);
}

// Round 3
// 1464.209 us; speedup vs baseline: 1.0415x; 1.0415x over previous
//
#include <hip/hip_runtime.h>
#include <math.h>

#define B_  4
#define S_  2048
#define D_  512
#define H_  8
#define DK  64
#define NBH (B_ * H_)
#define BS_ (B_ * S_)
#define LNEPS 1e-5f

typedef float fp32x4 __attribute__((ext_vector_type(4)));
typedef short bf16x8 __attribute__((ext_vector_type(8)));
typedef unsigned short u16x8 __attribute__((ext_vector_type(8)));

__device__ __forceinline__ unsigned short f2bf(float x) {
    unsigned u = __builtin_bit_cast(unsigned, x);
    u += 0x7FFFu + ((u >> 16) & 1u);
    return (unsigned short)(u >> 16);
}
__device__ __forceinline__ float bf2f(unsigned short h) {
    unsigned u = ((unsigned)h) << 16;
    return __builtin_bit_cast(float, u);
}

#define MFMA16(a, b, c) __builtin_amdgcn_mfma_f32_16x16x32_bf16((a), (b), (c), 0, 0, 0)

// ---------------------------------------------------------------------------
// K0: weight prep — wT[widx][2][512][512]: transpose to [n][k] and split hi/lo
// ---------------------------------------------------------------------------
__global__ __launch_bounds__(256)
void prep_w_kernel(const float* __restrict__ w0, const float* __restrict__ w1,
                   const float* __restrict__ w2, const float* __restrict__ w3,
                   unsigned short* __restrict__ wT) {
    int widx = blockIdx.z;
    const float* w = (widx == 0) ? w0 : (widx == 1) ? w1 : (widx == 2) ? w2 : w3;
    unsigned short* hi = wT + (size_t)widx * 2 * D_ * D_;
    unsigned short* lo = hi + (size_t)D_ * D_;
    __shared__ float t[64][65];
    int k0 = blockIdx.x * 64, n0 = blockIdx.y * 64;
    int tid = threadIdx.x;
    int r = tid >> 2, cq = (tid & 3) * 16;
#pragma unroll
    for (int j = 0; j < 16; j += 4) {
        float4 vv = *(const float4*)&w[(size_t)(k0 + r) * D_ + n0 + cq + j];
        t[r][cq + j] = vv.x; t[r][cq + j + 1] = vv.y;
        t[r][cq + j + 2] = vv.z; t[r][cq + j + 3] = vv.w;
    }
    __syncthreads();
    // write wT[n][k], 16 k's per thread
    u16x8 h0, h1, l0, l1;
#pragma unroll
    for (int j = 0; j < 8; ++j) {
        float x0 = t[cq + j][r];
        float x1 = t[cq + 8 + j][r];
        unsigned short hh0 = f2bf(x0), hh1 = f2bf(x1);
        h0[j] = hh0; h1[j] = hh1;
        l0[j] = f2bf(x0 - bf2f(hh0));
        l1[j] = f2bf(x1 - bf2f(hh1));
    }
    size_t o = (size_t)(n0 + r) * D_ + k0 + cq;
    *(u16x8*)&hi[o] = h0; *(u16x8*)&hi[o + 8] = h1;
    *(u16x8*)&lo[o] = l0; *(u16x8*)&lo[o + 8] = l1;
}

// ---------------------------------------------------------------------------
// K1: LayerNorm stats (mean, rsqrt(var+eps)) for q,k,v. One wave per row.
// ---------------------------------------------------------------------------
__global__ __launch_bounds__(256)
void ln_stats_kernel(const float* __restrict__ q, const float* __restrict__ k,
                     const float* __restrict__ v, float* __restrict__ stats) {
    int gwave = (blockIdx.x * 256 + threadIdx.x) >> 6;
    int lane  = threadIdx.x & 63;
    int which = gwave >> 13;
    int row   = gwave & 8191;
    const float* src = (which == 0) ? q : ((which == 1) ? k : v);
    const float4* p = reinterpret_cast<const float4*>(src + (size_t)row * D_);
    float4 a = p[lane];
    float4 b = p[lane + 64];
    float sum = a.x + a.y + a.z + a.w + b.x + b.y + b.z + b.w;
    float sq  = a.x*a.x + a.y*a.y + a.z*a.z + a.w*a.w
              + b.x*b.x + b.y*b.y + b.z*b.z + b.w*b.w;
#pragma unroll
    for (int off = 32; off > 0; off >>= 1) {
        sum += __shfl_down(sum, off);
        sq  += __shfl_down(sq,  off);
    }
    if (lane == 0) {
        float mu  = sum * (1.0f / D_);
        float var = sq * (1.0f / D_) - mu * mu;
        stats[(size_t)gwave * 2 + 0] = mu;
        stats[(size_t)gwave * 2 + 1] = rsqrtf(var + LNEPS);
    }
}

// ---------------------------------------------------------------------------
// K2: 8192x512x512 GEMM via MFMA bf16.
//   NSPLIT=3: bf16x3 split product (AhBh + AhBl + AlBh); NSPLIT=1: single.
//   DO_LN: apply per-row LN to A while staging.
//   EPI=0: head-split bf16 hi/lo output (qkv). EPI=1: fp32 (acc+bias)*ls.
// Tiles: 128x128 block, BK=32, 4 waves (2x2), 64x64 per wave.
// ---------------------------------------------------------------------------
template<int NSPLIT, bool DO_LN, int EPI>
__global__ __launch_bounds__(256)
void gemm512_kernel(const float* __restrict__ src, const unsigned short* __restrict__ wTbase,
                    const float* __restrict__ bias, const float* __restrict__ gamma,
                    const float* __restrict__ beta, const float* __restrict__ stats,
                    const float* __restrict__ ls,
                    unsigned short* __restrict__ dhi, unsigned short* __restrict__ dlo,
                    float* __restrict__ dfp) {
    __shared__ unsigned short Ah[128][40], Bh[128][40];
    __shared__ unsigned short Al[128][40], Bl[128][40];
    __shared__ float gs[D_], bs[D_];
    int tid = threadIdx.x;
    if (DO_LN) {
        gs[tid] = gamma[tid]; gs[tid + 256] = gamma[tid + 256];
        bs[tid] = beta[tid];  bs[tid + 256] = beta[tid + 256];
    }
    const unsigned short* wThi = wTbase;
    const unsigned short* wTlo = wTbase + (size_t)D_ * D_;
    int rb = blockIdx.x * 128, cb = blockIdx.y * 128;
    int arow = tid >> 1, ahalf = (tid & 1) * 16;
    float mu = 0.f, rsg = 1.f;
    if (DO_LN) {
        mu  = stats[(size_t)(rb + arow) * 2];
        rsg = stats[(size_t)(rb + arow) * 2 + 1];
    }
    int wid = tid >> 6, lane = tid & 63;
    int wm = wid >> 1, wn = wid & 1;
    int fr = lane & 15, fs = lane >> 4;
    fp32x4 acc[4][4];
#pragma unroll
    for (int i = 0; i < 4; ++i)
#pragma unroll
        for (int j = 0; j < 4; ++j)
#pragma unroll
            for (int e = 0; e < 4; ++e) acc[i][j][e] = 0.f;
    __syncthreads();

    for (int kt = 0; kt < 16; ++kt) {
        int k0 = kt * 32;
        {   // stage A (128 rows x 32 k): thread -> row=tid>>1, 16 k's
            float xv[16];
#pragma unroll
            for (int g = 0; g < 4; ++g) {
                float4 vv = *(const float4*)&src[(size_t)(rb + arow) * D_ + k0 + ahalf + g * 4];
                xv[g*4+0] = vv.x; xv[g*4+1] = vv.y; xv[g*4+2] = vv.z; xv[g*4+3] = vv.w;
            }
            u16x8 h0, h1, l0, l1;
#pragma unroll
            for (int j = 0; j < 8; ++j) {
                float a0 = xv[j], a1 = xv[8 + j];
                if (DO_LN) {
                    a0 = (a0 - mu) * rsg * gs[k0 + ahalf + j] + bs[k0 + ahalf + j];
                    a1 = (a1 - mu) * rsg * gs[k0 + ahalf + 8 + j] + bs[k0 + ahalf + 8 + j];
                }
                unsigned short hh0 = f2bf(a0), hh1 = f2bf(a1);
                h0[j] = hh0; h1[j] = hh1;
                if (NSPLIT == 3) {
                    l0[j] = f2bf(a0 - bf2f(hh0));
                    l1[j] = f2bf(a1 - bf2f(hh1));
                }
            }
            *(u16x8*)&Ah[arow][ahalf] = h0;
            *(u16x8*)&Ah[arow][ahalf + 8] = h1;
            if (NSPLIT == 3) {
                *(u16x8*)&Al[arow][ahalf] = l0;
                *(u16x8*)&Al[arow][ahalf + 8] = l1;
            }
        }
        {   // stage B (128 n-rows x 32 k) from pre-transposed/split wT
            size_t o = (size_t)(cb + arow) * D_ + k0 + ahalf;
            *(u16x8*)&Bh[arow][ahalf]     = *(const u16x8*)&wThi[o];
            *(u16x8*)&Bh[arow][ahalf + 8] = *(const u16x8*)&wThi[o + 8];
            if (NSPLIT == 3) {
                *(u16x8*)&Bl[arow][ahalf]     = *(const u16x8*)&wTlo[o];
                *(u16x8*)&Bl[arow][ahalf + 8] = *(const u16x8*)&wTlo[o + 8];
            }
        }
        __syncthreads();
        bf16x8 ah[4], al[4];
#pragma unroll
        for (int mt = 0; mt < 4; ++mt) {
            ah[mt] = *(const bf16x8*)&Ah[wm * 64 + mt * 16 + fr][fs * 8];
            if (NSPLIT == 3) al[mt] = *(const bf16x8*)&Al[wm * 64 + mt * 16 + fr][fs * 8];
        }
#pragma unroll
        for (int nt = 0; nt < 4; ++nt) {
            bf16x8 bh8 = *(const bf16x8*)&Bh[wn * 64 + nt * 16 + fr][fs * 8];
            if (NSPLIT == 3) {
                bf16x8 bl8 = *(const bf16x8*)&Bl[wn * 64 + nt * 16 + fr][fs * 8];
#pragma unroll
                for (int mt = 0; mt < 4; ++mt) {
                    acc[mt][nt] = MFMA16(ah[mt], bh8, acc[mt][nt]);
                    acc[mt][nt] = MFMA16(ah[mt], bl8, acc[mt][nt]);
                    acc[mt][nt] = MFMA16(al[mt], bh8, acc[mt][nt]);
                }
            } else {
#pragma unroll
                for (int mt = 0; mt < 4; ++mt)
                    acc[mt][nt] = MFMA16(ah[mt], bh8, acc[mt][nt]);
            }
        }
        __syncthreads();
    }
    // epilogue. C layout: col = lane&15, row = (lane>>4)*4 + reg
#pragma unroll
    for (int mt = 0; mt < 4; ++mt) {
#pragma unroll
        for (int nt = 0; nt < 4; ++nt) {
#pragma unroll
            for (int r = 0; r < 4; ++r) {
                int row = rb + wm * 64 + mt * 16 + fs * 4 + r;
                int col = cb + wn * 64 + nt * 16 + fr;
                float val = acc[mt][nt][r] + bias[col];
                if (EPI == 0) {
                    unsigned short h = f2bf(val);
                    unsigned short l = f2bf(val - bf2f(h));
                    int b = row >> 11, s = row & (S_ - 1);
                    int hh = col >> 6, dk = col & 63;
                    size_t o = ((size_t)(b * H_ + hh) * S_ + s) * DK + dk;
                    dhi[o] = h; dlo[o] = l;
                } else {
                    dfp[(size_t)row * D_ + col] = val * ls[col];
                }
            }
        }
    }
}

// ---------------------------------------------------------------------------
// K3: V^T prep — vT[bh][dk][key] from vh_hi[bh][key][dk] (for PV B-fragments)
// ---------------------------------------------------------------------------
__global__ __launch_bounds__(256)
void vtrans_kernel(const unsigned short* __restrict__ vhi, unsigned short* __restrict__ vT) {
    int bh = blockIdx.y;
    int k0 = blockIdx.x * 64;
    __shared__ unsigned short T[64][72];
    int tid = threadIdx.x;
    int r = tid >> 2, cq = (tid & 3) * 16;
    size_t ib = (size_t)bh * S_ * DK;
    *(u16x8*)&T[r][cq]     = *(const u16x8*)&vhi[ib + (size_t)(k0 + r) * DK + cq];
    *(u16x8*)&T[r][cq + 8] = *(const u16x8*)&vhi[ib + (size_t)(k0 + r) * DK + cq + 8];
    __syncthreads();
    u16x8 o0, o1;
#pragma unroll
    for (int j = 0; j < 8; ++j) { o0[j] = T[cq + j][r]; o1[j] = T[cq + 8 + j][r]; }
    size_t ob = (size_t)bh * DK * S_ + (size_t)r * S_ + k0 + cq;
    *(u16x8*)&vT[ob] = o0;
    *(u16x8*)&vT[ob + 8] = o1;
}

// ---------------------------------------------------------------------------
// K4: scores = qh @ kh^T * 0.125 + pos, mask -> -inf. bf16x3 MFMA.
// 128x128 tile per block, K=64 staged in two 32-slices. Raw scores -> attn.
// ---------------------------------------------------------------------------
__global__ __launch_bounds__(256)
void scores_kernel(const unsigned short* __restrict__ qhi, const unsigned short* __restrict__ qlo,
                   const unsigned short* __restrict__ khi, const unsigned short* __restrict__ klo,
                   const float* __restrict__ pos, const int* __restrict__ mask,
                   float* __restrict__ attn) {
    __shared__ unsigned short Qh[128][40], Ql[128][40], Kh[128][40], Kl[128][40];
    int bh = blockIdx.z;
    size_t ob = (size_t)bh * S_ * DK;
    int tid = threadIdx.x;
    int rb = blockIdx.x * 128, cb = blockIdx.y * 128;
    int srow = tid >> 1, sh = (tid & 1) * 16;
    int wid = tid >> 6, lane = tid & 63;
    int wm = wid >> 1, wn = wid & 1;
    int fr = lane & 15, fs = lane >> 4;
    fp32x4 acc[4][4];
#pragma unroll
    for (int i = 0; i < 4; ++i)
#pragma unroll
        for (int j = 0; j < 4; ++j)
#pragma unroll
            for (int e = 0; e < 4; ++e) acc[i][j][e] = 0.f;

    for (int kt = 0; kt < 2; ++kt) {
        int k0 = kt * 32;
        size_t oq = ob + (size_t)(rb + srow) * DK + k0 + sh;
        size_t ok = ob + (size_t)(cb + srow) * DK + k0 + sh;
        *(u16x8*)&Qh[srow][sh]     = *(const u16x8*)&qhi[oq];
        *(u16x8*)&Qh[srow][sh + 8] = *(const u16x8*)&qhi[oq + 8];
        *(u16x8*)&Ql[srow][sh]     = *(const u16x8*)&qlo[oq];
        *(u16x8*)&Ql[srow][sh + 8] = *(const u16x8*)&qlo[oq + 8];
        *(u16x8*)&Kh[srow][sh]     = *(const u16x8*)&khi[ok];
        *(u16x8*)&Kh[srow][sh + 8] = *(const u16x8*)&khi[ok + 8];
        *(u16x8*)&Kl[srow][sh]     = *(const u16x8*)&klo[ok];
        *(u16x8*)&Kl[srow][sh + 8] = *(const u16x8*)&klo[ok + 8];
        __syncthreads();
        bf16x8 ah[4], al[4];
#pragma unroll
        for (int mt = 0; mt < 4; ++mt) {
            ah[mt] = *(const bf16x8*)&Qh[wm * 64 + mt * 16 + fr][fs * 8];
            al[mt] = *(const bf16x8*)&Ql[wm * 64 + mt * 16 + fr][fs * 8];
        }
#pragma unroll
        for (int nt = 0; nt < 4; ++nt) {
            bf16x8 bh8 = *(const bf16x8*)&Kh[wn * 64 + nt * 16 + fr][fs * 8];
            bf16x8 bl8 = *(const bf16x8*)&Kl[wn * 64 + nt * 16 + fr][fs * 8];
#pragma unroll
            for (int mt = 0; mt < 4; ++mt) {
                acc[mt][nt] = MFMA16(ah[mt], bh8, acc[mt][nt]);
                acc[mt][nt] = MFMA16(ah[mt], bl8, acc[mt][nt]);
                acc[mt][nt] = MFMA16(al[mt], bh8, acc[mt][nt]);
            }
        }
        __syncthreads();
    }
#pragma unroll
    for (int mt = 0; mt < 4; ++mt) {
#pragma unroll
        for (int nt = 0; nt < 4; ++nt) {
#pragma unroll
            for (int r = 0; r < 4; ++r) {
                int m = rb + wm * 64 + mt * 16 + fs * 4 + r;
                int n = cb + wn * 64 + nt * 16 + fr;
                size_t pm = (size_t)m * S_ + n;
                float raw = acc[mt][nt][r] * 0.125f + pos[pm];
                if (mask[pm] == 0) raw = -__builtin_inff();
                attn[(size_t)bh * S_ * S_ + pm] = raw;
            }
        }
    }
}

// ---------------------------------------------------------------------------
// K5: fused softmax + PV. Block: 64 q-rows of one bh, full 2048-key span.
// Pass A: stream raw scores, online (max, sumexp) per row (thread-owned).
// Pass B: per 64-key tile: normalize -> write attn (fp32) + P bf16 -> MFMA
//         with V^T tile -> x.
// ---------------------------------------------------------------------------
__global__ __launch_bounds__(256)
void pv_softmax_kernel(float* __restrict__ attn, const unsigned short* __restrict__ vT,
                       float* __restrict__ x) {
    int rb = blockIdx.x * 64;
    int bh = blockIdx.y;
    float* Sb = attn + (size_t)bh * S_ * S_ + (size_t)rb * S_;
    int tid = threadIdx.x;
    int row = tid >> 2, q4 = tid & 3;
    float* prow = Sb + (size_t)row * S_;
    float m = -1e30f, l = 0.f;
    for (int j = 0; j < 128; ++j) {
        float4 vv = *(const float4*)&prow[q4 * 4 + j * 16];
        float vals[4] = {vv.x, vv.y, vv.z, vv.w};
#pragma unroll
        for (int e = 0; e < 4; ++e) {
            float nm = fmaxf(m, vals[e]);
            l = l * __expf(m - nm) + __expf(vals[e] - nm);
            m = nm;
        }
    }
#pragma unroll
    for (int off = 1; off < 4; off <<= 1) {
        float mo  = __shfl_xor(m, off);
        float lo_ = __shfl_xor(l, off);
        float nm = fmaxf(m, mo);
        l = l * __expf(m - nm) + lo_ * __expf(mo - nm);
        m = nm;
    }
    float invl = 1.0f / l;

    __shared__ unsigned short P[64][72];
    __shared__ unsigned short Vt[64][72];
    const unsigned short* vb = vT + (size_t)bh * DK * S_;
    int wid = tid >> 6, lane = tid & 63;
    int fr = lane & 15, fs = lane >> 4;
    fp32x4 acc[4];
#pragma unroll
    for (int nt = 0; nt < 4; ++nt)
#pragma unroll
        for (int e = 0; e < 4; ++e) acc[nt][e] = 0.f;

    for (int kt = 0; kt < 32; ++kt) {
        int c0 = kt * 64;
        u16x8 p0, p1;
#pragma unroll
        for (int g = 0; g < 4; ++g) {
            float4 vv = *(const float4*)&prow[c0 + q4 * 16 + g * 4];
            float4 ov;
            ov.x = __expf(vv.x - m) * invl;
            ov.y = __expf(vv.y - m) * invl;
            ov.z = __expf(vv.z - m) * invl;
            ov.w = __expf(vv.w - m) * invl;
            *(float4*)&prow[c0 + q4 * 16 + g * 4] = ov;
            if (g < 2) {
                p0[g*4+0] = f2bf(ov.x); p0[g*4+1] = f2bf(ov.y);
                p0[g*4+2] = f2bf(ov.z); p0[g*4+3] = f2bf(ov.w);
            } else {
                p1[(g-2)*4+0] = f2bf(ov.x); p1[(g-2)*4+1] = f2bf(ov.y);
                p1[(g-2)*4+2] = f2bf(ov.z); p1[(g-2)*4+3] = f2bf(ov.w);
            }
        }
        *(u16x8*)&P[row][q4 * 16]     = p0;
        *(u16x8*)&P[row][q4 * 16 + 8] = p1;
        // stage V^T tile: Vt[dk][key], dk-row = tid>>2
        size_t ov_ = (size_t)row * S_ + c0 + q4 * 16;
        *(u16x8*)&Vt[row][q4 * 16]     = *(const u16x8*)&vb[ov_];
        *(u16x8*)&Vt[row][q4 * 16 + 8] = *(const u16x8*)&vb[ov_ + 8];
        __syncthreads();
#pragma unroll
        for (int ks = 0; ks < 2; ++ks) {
            bf16x8 af = *(const bf16x8*)&P[wid * 16 + fr][ks * 32 + fs * 8];
#pragma unroll
            for (int nt = 0; nt < 4; ++nt) {
                bf16x8 bf = *(const bf16x8*)&Vt[nt * 16 + fr][ks * 32 + fs * 8];
                acc[nt] = MFMA16(af, bf, acc[nt]);
            }
        }
        __syncthreads();
    }
    int b = bh >> 3, h = bh & 7;
#pragma unroll
    for (int nt = 0; nt < 4; ++nt)
#pragma unroll
        for (int r = 0; r < 4; ++r) {
            int qrow = rb + wid * 16 + fs * 4 + r;
            x[((size_t)b * S_ + qrow) * D_ + h * DK + nt * 16 + fr] = acc[nt][r];
        }
}

// ---------------------------------------------------------------------------
extern "C" void kernel_launch(void* const* d_in, const int* in_sizes, int n_in,
                              void* d_out, int out_size, void* d_ws, size_t ws_size,
                              hipStream_t stream) {
    const float* q    = (const float*)d_in[0];
    const float* k    = (const float*)d_in[1];
    const float* v    = (const float*)d_in[2];
    const int*   mask = (const int*)  d_in[3];
    const float* pos  = (const float*)d_in[4];
    const float* ln_g = (const float*)d_in[5];
    const float* ln_b = (const float*)d_in[6];
    const float* wq   = (const float*)d_in[7];
    const float* bq   = (const float*)d_in[8];
    const float* wk   = (const float*)d_in[9];
    const float* bk   = (const float*)d_in[10];
    const float* wv   = (const float*)d_in[11];
    const float* bv   = (const float*)d_in[12];
    const float* wo   = (const float*)d_in[13];
    const float* bo   = (const float*)d_in[14];
    const float* ls   = (const float*)d_in[15];

    float* out  = (float*)d_out;
    float* attn = out + (size_t)B_ * S_ * D_;

    const size_t NW = (size_t)D_ * D_;          // 262144
    const size_t NH = (size_t)NBH * S_ * DK;    // 4194304
    unsigned short* wT  = (unsigned short*)d_ws;    // [4][2][512][512]
    unsigned short* qhh = wT  + 8 * NW;
    unsigned short* qhl = qhh + NH;
    unsigned short* khh = qhl + NH;
    unsigned short* khl = khh + NH;
    unsigned short* vhh = khl + NH;
    unsigned short* vhl = vhh + NH;
    unsigned short* vTt = vhl + NH;                 // [32][64][2048]
    float* stats = (float*)(vTt + NH);              // [3][8192][2]
    float* x     = stats + (size_t)3 * BS_ * 2;     // [8192][512]

    prep_w_kernel<<<dim3(8, 8, 4), 256, 0, stream>>>(wq, wk, wv, wo, wT);
    ln_stats_kernel<<<6144, 256, 0, stream>>>(q, k, v, stats);

    dim3 gproj(64, 4);
    gemm512_kernel<3, true, 0><<<gproj, 256, 0, stream>>>(
        q, wT + 0 * NW, bq, ln_g, ln_b, stats, nullptr, qhh, qhl, nullptr);
    gemm512_kernel<3, true, 0><<<gproj, 256, 0, stream>>>(
        k, wT + 2 * NW, bk, ln_g, ln_b, stats + 2 * BS_, nullptr, khh, khl, nullptr);
    gemm512_kernel<3, true, 0><<<gproj, 256, 0, stream>>>(
        v, wT + 4 * NW, bv, ln_g, ln_b, stats + 4 * BS_, nullptr, vhh, vhl, nullptr);

    vtrans_kernel<<<dim3(32, 32), 256, 0, stream>>>(vhh, vTt);

    scores_kernel<<<dim3(16, 16, 32), 256, 0, stream>>>(qhh, qhl, khh, khl, pos, mask, attn);
    pv_softmax_kernel<<<dim3(32, 32), 256, 0, stream>>>(attn, vTt, x);

    gemm512_kernel<1, false, 1><<<gproj, 256, 0, stream>>>(
        x, wT + 6 * NW, bo, nullptr, nullptr, nullptr, ls, nullptr, nullptr, out);
}

// Round 6
// 1144.044 us; speedup vs baseline: 1.3329x; 1.2799x over previous
//
#include <hip/hip_runtime.h>
#include <math.h>

#define B_  4
#define S_  2048
#define D_  512
#define H_  8
#define DK  64
#define NBH (B_ * H_)
#define BS_ (B_ * S_)
#define LNEPS 1e-5f
#define NEGBIG (-1e30f)

typedef float fp32x4 __attribute__((ext_vector_type(4)));
typedef short bf16x8 __attribute__((ext_vector_type(8)));
typedef unsigned short u16x8 __attribute__((ext_vector_type(8)));

__device__ __forceinline__ unsigned short f2bf(float x) {
    unsigned u = __builtin_bit_cast(unsigned, x);
    u += 0x7FFFu + ((u >> 16) & 1u);
    return (unsigned short)(u >> 16);
}
__device__ __forceinline__ float bf2f(unsigned short h) {
    unsigned u = ((unsigned)h) << 16;
    return __builtin_bit_cast(float, u);
}

#define MFMA16(a, b, c) __builtin_amdgcn_mfma_f32_16x16x32_bf16((a), (b), (c), 0, 0, 0)

// ---------------------------------------------------------------------------
// K0: weight prep — wT[widx][2][512][512]: transpose to [n][k] and split hi/lo
// ---------------------------------------------------------------------------
__global__ __launch_bounds__(256)
void prep_w_kernel(const float* __restrict__ w0, const float* __restrict__ w1,
                   const float* __restrict__ w2, const float* __restrict__ w3,
                   unsigned short* __restrict__ wT) {
    int widx = blockIdx.z;
    const float* w = (widx == 0) ? w0 : (widx == 1) ? w1 : (widx == 2) ? w2 : w3;
    unsigned short* hi = wT + (size_t)widx * 2 * D_ * D_;
    unsigned short* lo = hi + (size_t)D_ * D_;
    __shared__ float t[64][65];
    int k0 = blockIdx.x * 64, n0 = blockIdx.y * 64;
    int tid = threadIdx.x;
    int r = tid >> 2, cq = (tid & 3) * 16;
#pragma unroll
    for (int j = 0; j < 16; j += 4) {
        float4 vv = *(const float4*)&w[(size_t)(k0 + r) * D_ + n0 + cq + j];
        t[r][cq + j] = vv.x; t[r][cq + j + 1] = vv.y;
        t[r][cq + j + 2] = vv.z; t[r][cq + j + 3] = vv.w;
    }
    __syncthreads();
    u16x8 h0, h1, l0, l1;
#pragma unroll
    for (int j = 0; j < 8; ++j) {
        float x0 = t[cq + j][r];
        float x1 = t[cq + 8 + j][r];
        unsigned short hh0 = f2bf(x0), hh1 = f2bf(x1);
        h0[j] = hh0; h1[j] = hh1;
        l0[j] = f2bf(x0 - bf2f(hh0));
        l1[j] = f2bf(x1 - bf2f(hh1));
    }
    size_t o = (size_t)(n0 + r) * D_ + k0 + cq;
    *(u16x8*)&hi[o] = h0; *(u16x8*)&hi[o + 8] = h1;
    *(u16x8*)&lo[o] = l0; *(u16x8*)&lo[o + 8] = l1;
}

// ---------------------------------------------------------------------------
// K1: LayerNorm stats (mean, rsqrt(var+eps)) for q,k,v. One wave per row.
// ---------------------------------------------------------------------------
__global__ __launch_bounds__(256)
void ln_stats_kernel(const float* __restrict__ q, const float* __restrict__ k,
                     const float* __restrict__ v, float* __restrict__ stats) {
    int gwave = (blockIdx.x * 256 + threadIdx.x) >> 6;
    int lane  = threadIdx.x & 63;
    int which = gwave >> 13;
    int row   = gwave & 8191;
    const float* src = (which == 0) ? q : ((which == 1) ? k : v);
    const float4* p = reinterpret_cast<const float4*>(src + (size_t)row * D_);
    float4 a = p[lane];
    float4 b = p[lane + 64];
    float sum = a.x + a.y + a.z + a.w + b.x + b.y + b.z + b.w;
    float sq  = a.x*a.x + a.y*a.y + a.z*a.z + a.w*a.w
              + b.x*b.x + b.y*b.y + b.z*b.z + b.w*b.w;
#pragma unroll
    for (int off = 32; off > 0; off >>= 1) {
        sum += __shfl_down(sum, off);
        sq  += __shfl_down(sq,  off);
    }
    if (lane == 0) {
        float mu  = sum * (1.0f / D_);
        float var = sq * (1.0f / D_) - mu * mu;
        stats[(size_t)gwave * 2 + 0] = mu;
        stats[(size_t)gwave * 2 + 1] = rsqrtf(var + LNEPS);
    }
}

// ---------------------------------------------------------------------------
// K1b: biasM[m][n] = mask ? pos : -1e30  (pre-scaled additive score bias)
// ---------------------------------------------------------------------------
__global__ __launch_bounds__(256)
void bias_kernel(const float* __restrict__ pos, const int* __restrict__ mask,
                 float* __restrict__ biasM) {
    size_t i = ((size_t)blockIdx.x * 256 + threadIdx.x) * 4;
    float4 p = *(const float4*)&pos[i];
    int4 mk = *(const int4*)&mask[i];
    float4 o;
    o.x = mk.x ? p.x : NEGBIG;
    o.y = mk.y ? p.y : NEGBIG;
    o.z = mk.z ? p.z : NEGBIG;
    o.w = mk.w ? p.w : NEGBIG;
    *(float4*)&biasM[i] = o;
}

// ---------------------------------------------------------------------------
// K2: 8192x512x512 GEMM via MFMA bf16 (NSPLIT=3 split / 1 plain).
// ---------------------------------------------------------------------------
template<int NSPLIT, bool DO_LN, int EPI>
__global__ __launch_bounds__(256)
void gemm512_kernel(const float* __restrict__ src, const unsigned short* __restrict__ wTbase,
                    const float* __restrict__ bias, const float* __restrict__ gamma,
                    const float* __restrict__ beta, const float* __restrict__ stats,
                    const float* __restrict__ ls,
                    unsigned short* __restrict__ dhi, unsigned short* __restrict__ dlo,
                    float* __restrict__ dfp) {
    __shared__ unsigned short Ah[128][40], Bh[128][40];
    __shared__ unsigned short Al[128][40], Bl[128][40];
    __shared__ float gs[D_], bs[D_];
    int tid = threadIdx.x;
    if (DO_LN) {
        gs[tid] = gamma[tid]; gs[tid + 256] = gamma[tid + 256];
        bs[tid] = beta[tid];  bs[tid + 256] = beta[tid + 256];
    }
    const unsigned short* wThi = wTbase;
    const unsigned short* wTlo = wTbase + (size_t)D_ * D_;
    int rb = blockIdx.x * 128, cb = blockIdx.y * 128;
    int arow = tid >> 1, ahalf = (tid & 1) * 16;
    float mu = 0.f, rsg = 1.f;
    if (DO_LN) {
        mu  = stats[(size_t)(rb + arow) * 2];
        rsg = stats[(size_t)(rb + arow) * 2 + 1];
    }
    int wid = tid >> 6, lane = tid & 63;
    int wm = wid >> 1, wn = wid & 1;
    int fr = lane & 15, fs = lane >> 4;
    fp32x4 acc[4][4];
#pragma unroll
    for (int i = 0; i < 4; ++i)
#pragma unroll
        for (int j = 0; j < 4; ++j)
#pragma unroll
            for (int e = 0; e < 4; ++e) acc[i][j][e] = 0.f;
    __syncthreads();

    for (int kt = 0; kt < 16; ++kt) {
        int k0 = kt * 32;
        {
            float xv[16];
#pragma unroll
            for (int g = 0; g < 4; ++g) {
                float4 vv = *(const float4*)&src[(size_t)(rb + arow) * D_ + k0 + ahalf + g * 4];
                xv[g*4+0] = vv.x; xv[g*4+1] = vv.y; xv[g*4+2] = vv.z; xv[g*4+3] = vv.w;
            }
            u16x8 h0, h1, l0, l1;
#pragma unroll
            for (int j = 0; j < 8; ++j) {
                float a0 = xv[j], a1 = xv[8 + j];
                if (DO_LN) {
                    a0 = (a0 - mu) * rsg * gs[k0 + ahalf + j] + bs[k0 + ahalf + j];
                    a1 = (a1 - mu) * rsg * gs[k0 + ahalf + 8 + j] + bs[k0 + ahalf + 8 + j];
                }
                unsigned short hh0 = f2bf(a0), hh1 = f2bf(a1);
                h0[j] = hh0; h1[j] = hh1;
                if (NSPLIT == 3) {
                    l0[j] = f2bf(a0 - bf2f(hh0));
                    l1[j] = f2bf(a1 - bf2f(hh1));
                }
            }
            *(u16x8*)&Ah[arow][ahalf] = h0;
            *(u16x8*)&Ah[arow][ahalf + 8] = h1;
            if (NSPLIT == 3) {
                *(u16x8*)&Al[arow][ahalf] = l0;
                *(u16x8*)&Al[arow][ahalf + 8] = l1;
            }
        }
        {
            size_t o = (size_t)(cb + arow) * D_ + k0 + ahalf;
            *(u16x8*)&Bh[arow][ahalf]     = *(const u16x8*)&wThi[o];
            *(u16x8*)&Bh[arow][ahalf + 8] = *(const u16x8*)&wThi[o + 8];
            if (NSPLIT == 3) {
                *(u16x8*)&Bl[arow][ahalf]     = *(const u16x8*)&wTlo[o];
                *(u16x8*)&Bl[arow][ahalf + 8] = *(const u16x8*)&wTlo[o + 8];
            }
        }
        __syncthreads();
        bf16x8 ah[4], al[4];
#pragma unroll
        for (int mt = 0; mt < 4; ++mt) {
            ah[mt] = *(const bf16x8*)&Ah[wm * 64 + mt * 16 + fr][fs * 8];
            if (NSPLIT == 3) al[mt] = *(const bf16x8*)&Al[wm * 64 + mt * 16 + fr][fs * 8];
        }
#pragma unroll
        for (int nt = 0; nt < 4; ++nt) {
            bf16x8 bh8 = *(const bf16x8*)&Bh[wn * 64 + nt * 16 + fr][fs * 8];
            if (NSPLIT == 3) {
                bf16x8 bl8 = *(const bf16x8*)&Bl[wn * 64 + nt * 16 + fr][fs * 8];
#pragma unroll
                for (int mt = 0; mt < 4; ++mt) {
                    acc[mt][nt] = MFMA16(ah[mt], bh8, acc[mt][nt]);
                    acc[mt][nt] = MFMA16(ah[mt], bl8, acc[mt][nt]);
                    acc[mt][nt] = MFMA16(al[mt], bh8, acc[mt][nt]);
                }
            } else {
#pragma unroll
                for (int mt = 0; mt < 4; ++mt)
                    acc[mt][nt] = MFMA16(ah[mt], bh8, acc[mt][nt]);
            }
        }
        __syncthreads();
    }
#pragma unroll
    for (int mt = 0; mt < 4; ++mt) {
#pragma unroll
        for (int nt = 0; nt < 4; ++nt) {
#pragma unroll
            for (int r = 0; r < 4; ++r) {
                int row = rb + wm * 64 + mt * 16 + fs * 4 + r;
                int col = cb + wn * 64 + nt * 16 + fr;
                float val = acc[mt][nt][r] + bias[col];
                if (EPI == 0) {
                    unsigned short h = f2bf(val);
                    unsigned short l = f2bf(val - bf2f(h));
                    int b = row >> 11, s = row & (S_ - 1);
                    int hh = col >> 6, dk = col & 63;
                    size_t o = ((size_t)(b * H_ + hh) * S_ + s) * DK + dk;
                    dhi[o] = h; dlo[o] = l;
                } else {
                    dfp[(size_t)row * D_ + col] = val * ls[col];
                }
            }
        }
    }
}

// ---------------------------------------------------------------------------
// K3: V^T prep — vT[bh][dk][key] from vh_hi[bh][key][dk]
// ---------------------------------------------------------------------------
__global__ __launch_bounds__(256)
void vtrans_kernel(const unsigned short* __restrict__ vhi, unsigned short* __restrict__ vT) {
    int bh = blockIdx.y;
    int k0 = blockIdx.x * 64;
    __shared__ unsigned short T[64][72];
    int tid = threadIdx.x;
    int r = tid >> 2, cq = (tid & 3) * 16;
    size_t ib = (size_t)bh * S_ * DK;
    *(u16x8*)&T[r][cq]     = *(const u16x8*)&vhi[ib + (size_t)(k0 + r) * DK + cq];
    *(u16x8*)&T[r][cq + 8] = *(const u16x8*)&vhi[ib + (size_t)(k0 + r) * DK + cq + 8];
    __syncthreads();
    u16x8 o0, o1;
#pragma unroll
    for (int j = 0; j < 8; ++j) { o0[j] = T[cq + j][r]; o1[j] = T[cq + 8 + j][r]; }
    size_t ob = (size_t)bh * DK * S_ + (size_t)r * S_ + k0 + cq;
    *(u16x8*)&vT[ob] = o0;
    *(u16x8*)&vT[ob + 8] = o1;
}

// ---------------------------------------------------------------------------
// K4: fused flash attention. Block = one bh x 64 q-rows; 4 waves x 16 rows.
// Phase 1: stream K tiles (64 keys), QK^T bf16x3 -> fragment-level online
//          max/sum (shfl_xor butterflies; no serial chain).
// Phase 2: recompute S tiles, p = exp(s-m)/l -> write attn fp32 ONCE,
//          P->bf16 via per-wave LDS transpose -> PV MFMA -> x.
// Raw-score global round-trip (2x537 MB) eliminated.
// ---------------------------------------------------------------------------
__global__ __launch_bounds__(256)
void flash_kernel(const unsigned short* __restrict__ qhi, const unsigned short* __restrict__ qlo,
                  const unsigned short* __restrict__ khi, const unsigned short* __restrict__ klo,
                  const float* __restrict__ biasM, const unsigned short* __restrict__ vT,
                  float* __restrict__ attn, float* __restrict__ x) {
    __shared__ unsigned short Kh[64][68];
    __shared__ unsigned short Kl[64][68];
    __shared__ unsigned short Pl[4][16][68];
    int tid = threadIdx.x;
    int rb = blockIdx.x * 64;
    int bh = blockIdx.y;
    size_t hb = (size_t)bh * S_ * DK;
    int wid = tid >> 6, lane = tid & 63;
    int fr = lane & 15, fs = lane >> 4;
    int m0 = rb + wid * 16;

    // Q A-fragments (row = fr, k = fs*8+j within 32-slice), hi+lo
    bf16x8 qah[2], qal[2];
#pragma unroll
    for (int ks = 0; ks < 2; ++ks) {
        size_t o = hb + (size_t)(m0 + fr) * DK + ks * 32 + fs * 8;
        qah[ks] = *(const bf16x8*)&qhi[o];
        qal[ks] = *(const bf16x8*)&qlo[o];
    }
    int krow = tid >> 2, kcq = (tid & 3) * 16;

    float mrun[4], lrun[4];
#pragma unroll
    for (int r = 0; r < 4; ++r) { mrun[r] = NEGBIG; lrun[r] = 0.f; }

    // ---------------- phase 1: running max / sumexp ----------------
    for (int kt = 0; kt < 32; ++kt) {
        int c0 = kt * 64;
        __syncthreads();
        {
            size_t o = hb + (size_t)(c0 + krow) * DK + kcq;
            *(u16x8*)&Kh[krow][kcq]     = *(const u16x8*)&khi[o];
            *(u16x8*)&Kh[krow][kcq + 8] = *(const u16x8*)&khi[o + 8];
            *(u16x8*)&Kl[krow][kcq]     = *(const u16x8*)&klo[o];
            *(u16x8*)&Kl[krow][kcq + 8] = *(const u16x8*)&klo[o + 8];
        }
        __syncthreads();
        fp32x4 acc[4];
#pragma unroll
        for (int nt = 0; nt < 4; ++nt) {
            fp32x4 a = {0.f, 0.f, 0.f, 0.f};
#pragma unroll
            for (int ks = 0; ks < 2; ++ks) {
                bf16x8 kbh = *(const bf16x8*)&Kh[nt * 16 + fr][ks * 32 + fs * 8];
                bf16x8 kbl = *(const bf16x8*)&Kl[nt * 16 + fr][ks * 32 + fs * 8];
                a = MFMA16(qah[ks], kbh, a);
                a = MFMA16(qah[ks], kbl, a);
                a = MFMA16(qal[ks], kbh, a);
            }
            acc[nt] = a;
        }
#pragma unroll
        for (int r = 0; r < 4; ++r) {
            const float* brow = biasM + (size_t)(m0 + fs * 4 + r) * S_ + fr;
            float s0 = acc[0][r] * 0.125f + brow[c0];
            float s1 = acc[1][r] * 0.125f + brow[c0 + 16];
            float s2 = acc[2][r] * 0.125f + brow[c0 + 32];
            float s3 = acc[3][r] * 0.125f + brow[c0 + 48];
            float tmax = fmaxf(fmaxf(s0, s1), fmaxf(s2, s3));
#pragma unroll
            for (int msk = 1; msk < 16; msk <<= 1)
                tmax = fmaxf(tmax, __shfl_xor(tmax, msk));
            float nm = fmaxf(mrun[r], tmax);
            float ps = __expf(s0 - nm) + __expf(s1 - nm) + __expf(s2 - nm) + __expf(s3 - nm);
#pragma unroll
            for (int msk = 1; msk < 16; msk <<= 1)
                ps += __shfl_xor(ps, msk);
            lrun[r] = lrun[r] * __expf(mrun[r] - nm) + ps;
            mrun[r] = nm;
        }
    }

    float invl[4];
#pragma unroll
    for (int r = 0; r < 4; ++r) invl[r] = 1.0f / lrun[r];

    // ---------------- phase 2: recompute, write attn, PV ----------------
    fp32x4 acc2[4];
#pragma unroll
    for (int nt = 0; nt < 4; ++nt)
#pragma unroll
        for (int e = 0; e < 4; ++e) acc2[nt][e] = 0.f;

    const unsigned short* vb = vT + (size_t)bh * DK * S_;
    float* ab = attn + (size_t)bh * S_ * S_;

    for (int kt = 0; kt < 32; ++kt) {
        int c0 = kt * 64;
        __syncthreads();
        {
            size_t o = hb + (size_t)(c0 + krow) * DK + kcq;
            *(u16x8*)&Kh[krow][kcq]     = *(const u16x8*)&khi[o];
            *(u16x8*)&Kh[krow][kcq + 8] = *(const u16x8*)&khi[o + 8];
            *(u16x8*)&Kl[krow][kcq]     = *(const u16x8*)&klo[o];
            *(u16x8*)&Kl[krow][kcq + 8] = *(const u16x8*)&klo[o + 8];
        }
        __syncthreads();
        fp32x4 acc[4];
#pragma unroll
        for (int nt = 0; nt < 4; ++nt) {
            fp32x4 a = {0.f, 0.f, 0.f, 0.f};
#pragma unroll
            for (int ks = 0; ks < 2; ++ks) {
                bf16x8 kbh = *(const bf16x8*)&Kh[nt * 16 + fr][ks * 32 + fs * 8];
                bf16x8 kbl = *(const bf16x8*)&Kl[nt * 16 + fr][ks * 32 + fs * 8];
                a = MFMA16(qah[ks], kbh, a);
                a = MFMA16(qah[ks], kbl, a);
                a = MFMA16(qal[ks], kbh, a);
            }
            acc[nt] = a;
        }
#pragma unroll
        for (int r = 0; r < 4; ++r) {
            int m = m0 + fs * 4 + r;
            const float* brow = biasM + (size_t)m * S_ + fr;
            float* arow = ab + (size_t)m * S_ + fr;
#pragma unroll
            for (int nt = 0; nt < 4; ++nt) {
                float s = acc[nt][r] * 0.125f + brow[c0 + nt * 16];
                float p = __expf(s - mrun[r]) * invl[r];
                arow[c0 + nt * 16] = p;
                Pl[wid][fs * 4 + r][nt * 16 + fr] = f2bf(p);
            }
        }
        // P is per-wave; LDS write->read hazard handled by compiler waitcnt.
#pragma unroll
        for (int ks2 = 0; ks2 < 2; ++ks2) {
            bf16x8 pa = *(const bf16x8*)&Pl[wid][fr][ks2 * 32 + fs * 8];
#pragma unroll
            for (int nt2 = 0; nt2 < 4; ++nt2) {
                bf16x8 vf = *(const bf16x8*)&vb[(size_t)(nt2 * 16 + fr) * S_ + c0 + ks2 * 32 + fs * 8];
                acc2[nt2] = MFMA16(pa, vf, acc2[nt2]);
            }
        }
    }

    int b = bh >> 3, h = bh & 7;
#pragma unroll
    for (int nt2 = 0; nt2 < 4; ++nt2)
#pragma unroll
        for (int r = 0; r < 4; ++r)
            x[((size_t)b * S_ + m0 + fs * 4 + r) * D_ + h * DK + nt2 * 16 + fr] = acc2[nt2][r];
}

// ---------------------------------------------------------------------------
extern "C" void kernel_launch(void* const* d_in, const int* in_sizes, int n_in,
                              void* d_out, int out_size, void* d_ws, size_t ws_size,
                              hipStream_t stream) {
    const float* q    = (const float*)d_in[0];
    const float* k    = (const float*)d_in[1];
    const float* v    = (const float*)d_in[2];
    const int*   mask = (const int*)  d_in[3];
    const float* pos  = (const float*)d_in[4];
    const float* ln_g = (const float*)d_in[5];
    const float* ln_b = (const float*)d_in[6];
    const float* wq   = (const float*)d_in[7];
    const float* bq   = (const float*)d_in[8];
    const float* wk   = (const float*)d_in[9];
    const float* bk   = (const float*)d_in[10];
    const float* wv   = (const float*)d_in[11];
    const float* bv   = (const float*)d_in[12];
    const float* wo   = (const float*)d_in[13];
    const float* bo   = (const float*)d_in[14];
    const float* ls   = (const float*)d_in[15];

    float* out  = (float*)d_out;
    float* attn = out + (size_t)B_ * S_ * D_;

    const size_t NW = (size_t)D_ * D_;
    const size_t NH = (size_t)NBH * S_ * DK;
    unsigned short* wT  = (unsigned short*)d_ws;    // [4][2][512][512]
    unsigned short* qhh = wT  + 8 * NW;
    unsigned short* qhl = qhh + NH;
    unsigned short* khh = qhl + NH;
    unsigned short* khl = khh + NH;
    unsigned short* vhh = khl + NH;
    unsigned short* vhl = vhh + NH;
    unsigned short* vTt = vhl + NH;                 // [32][64][2048]
    float* stats = (float*)(vTt + NH);              // [3][8192][2]
    float* x     = stats + (size_t)3 * BS_ * 2;     // [8192][512]
    float* biasM = x + (size_t)BS_ * D_;            // [2048][2048]

    prep_w_kernel<<<dim3(8, 8, 4), 256, 0, stream>>>(wq, wk, wv, wo, wT);
    ln_stats_kernel<<<6144, 256, 0, stream>>>(q, k, v, stats);
    bias_kernel<<<4096, 256, 0, stream>>>(pos, mask, biasM);

    dim3 gproj(64, 4);
    gemm512_kernel<3, true, 0><<<gproj, 256, 0, stream>>>(
        q, wT + 0 * NW, bq, ln_g, ln_b, stats, nullptr, qhh, qhl, nullptr);
    gemm512_kernel<3, true, 0><<<gproj, 256, 0, stream>>>(
        k, wT + 2 * NW, bk, ln_g, ln_b, stats + 2 * BS_, nullptr, khh, khl, nullptr);
    gemm512_kernel<3, true, 0><<<gproj, 256, 0, stream>>>(
        v, wT + 4 * NW, bv, ln_g, ln_b, stats + 4 * BS_, nullptr, vhh, vhl, nullptr);

    vtrans_kernel<<<dim3(32, 32), 256, 0, stream>>>(vhh, vTt);

    flash_kernel<<<dim3(32, 32), 256, 0, stream>>>(qhh, qhl, khh, khl, biasM, vTt, attn, x);

    gemm512_kernel<1, false, 1><<<gproj, 256, 0, stream>>>(
        x, wT + 6 * NW, bo, nullptr, nullptr, nullptr, ls, nullptr, nullptr, out);
}